// Round 8
// baseline (211.276 us; speedup 1.0000x reference)
//
#include <hip/hip_runtime.h>
#include <cmath>

#define T_LEN   480000
#define BATCH   64
#define CHUNK   16                       /* samples per thread */
#define WARM    16                       /* |pole|=0.414 -> 0.414^16 ~ 7.6e-7 */
#define TPB     256
#define TS      (TPB * CHUNK)            /* 4096 samples per tile */
#define TPR     ((T_LEN + TS - 1) / TS)  /* 118 tiles per row */
#define NLOAD_MAX (TS + WARM)            /* 4112 */
#define NITER   ((NLOAD_MAX + TPB * 4 - 1) / (TPB * 4))   /* 5 */
/* quad skew: +4 floats per 32 -> aligned float4 stays contiguous, all
   access patterns bank-uniform (8 lanes/quad). */
#define LDS_SLOTS (NLOAD_MAX + ((NLOAD_MAX >> 5) << 2))  /* 18.5 KB */

/* native vector type: __builtin_nontemporal_* rejects HIP_vector_type */
typedef float f32x4 __attribute__((ext_vector_type(4)));

__device__ __forceinline__ int slot4(int i) { return i + ((i >> 5) << 2); }

#define STEP(XN, YN)                                            \
    {                                                           \
        float u_ = fmaf(B0, (XN), fmaf(B1, x1, B2 * x2));       \
        (YN) = fmaf(-A1, y1, fmaf(-A2, y2, u_));                \
        x2 = x1; x1 = (XN); y2 = y1; y1 = (YN);                 \
    }

/* R8 theory: FETCH_SIZE has been ~60MB vs 123MB ideal all session -> half
   the input is L3-resident when the kernel starts.  R5's nt LOADS threw
   that residency away while its nt STORES protected it (the two nearly
   cancelled, +5us).  This round: REGULAR loads (hit the L3-resident x),
   nt stores only (write stream doesn't evict x).  One variable vs R5.
   Predict: FETCH << 60MB and dur ~72 -> ~50-55us.  If FETCH stays ~60MB
   and dur ~72: reads are platform-pinned at ~2.5TB/s (runtime copyBuffer
   shows the same) -> roofline. */

__global__ __launch_bounds__(TPB) void allpass_kernel(
    const float* __restrict__ x, float* __restrict__ y,
    float B0, float B1, float B2, float A1, float A2)
{
    __shared__ __align__(16) float lds[LDS_SLOTS];
    const int tid  = threadIdx.x;
    const int row  = blockIdx.x / TPR;
    const int tb   = blockIdx.x % TPR;
    const int sbase = tb * TS;
    const int ns   = min(TS, T_LEN - sbase);      /* 4096, last tile 768 */
    const float* __restrict__ xr = x + (size_t)row * T_LEN + sbase;
    float* __restrict__ yr       = y + (size_t)row * T_LEN + sbase;
    const int nload = ns + WARM;

    /* ---- phase 1: cached loads issued back-to-back, then ds_writes ---- */
    f32x4 vbuf[NITER];
    #pragma unroll
    for (int j = 0; j < NITER; ++j) {
        const int i4 = tid * 4 + j * (TPB * 4);
        if (i4 < nload) {
            if (tb == 0 && i4 < WARM)
                vbuf[j] = (f32x4){0.f, 0.f, 0.f, 0.f};
            else
                vbuf[j] = *(const f32x4*)(xr - WARM + i4);   /* REGULAR load */
        }
    }
    #pragma unroll
    for (int j = 0; j < NITER; ++j) {
        const int i4 = tid * 4 + j * (TPB * 4);
        if (i4 < nload)
            *(f32x4*)&lds[slot4(i4)] = vbuf[j];
    }
    __syncthreads();

    /* ---- phase 2: private recurrence, 16 warm-up + 16 real steps ---- */
    f32x4 yq[CHUNK / 4];
    const int ls = tid * CHUNK;
    const bool active = (ls < ns);
    if (active) {
        float x1 = 0.f, x2 = 0.f, y1 = 0.f, y2 = 0.f;
        #pragma unroll
        for (int t4 = 0; t4 < WARM; t4 += 4) {
            f32x4 xv = *(const f32x4*)&lds[slot4(ls + t4)];
            float t;
            STEP(xv.x, t); STEP(xv.y, t); STEP(xv.z, t); STEP(xv.w, t);
        }
        #pragma unroll
        for (int t4 = 0; t4 < CHUNK; t4 += 4) {
            f32x4 xv = *(const f32x4*)&lds[slot4(ls + WARM + t4)];
            f32x4 yv;
            STEP(xv.x, yv.x); STEP(xv.y, yv.y);
            STEP(xv.z, yv.z); STEP(xv.w, yv.w);
            yq[t4 / 4] = yv;
        }
    }
    __syncthreads();                              /* LDS x-reads done */

    /* ---- phase 3: stage y through LDS, then lane-contiguous nt stores
       (full 64B lines per wave-instruction -> posted, no allocate) ---- */
    if (active) {
        #pragma unroll
        for (int t4 = 0; t4 < CHUNK; t4 += 4)
            *(f32x4*)&lds[slot4(ls + t4)] = yq[t4 / 4];
    }
    __syncthreads();

    #pragma unroll
    for (int j = 0; j < NITER - 1; ++j) {         /* 4 iters cover TS */
        const int i4 = tid * 4 + j * (TPB * 4);
        if (i4 < ns) {
            f32x4 v = *(const f32x4*)&lds[slot4(i4)];
            __builtin_nontemporal_store(v, (f32x4*)(yr + i4));
        }
    }
}

extern "C" void kernel_launch(void* const* d_in, const int* in_sizes, int n_in,
                              void* d_out, int out_size, void* d_ws, size_t ws_size,
                              hipStream_t stream) {
    const float* x = (const float*)d_in[0];
    float* y = (float*)d_out;

    const double sample_rate = 16000.0, central_freq = 4000.0, Q = 0.707;
    const double w0 = 2.0 * M_PI * central_freq / sample_rate;
    const double alpha = sin(w0) / (2.0 * Q);
    const double cw = cos(w0);
    const double a0 = 1.0 + alpha;
    const float B0 = (float)((1.0 - alpha) / a0);
    const float B1 = (float)((-2.0 * cw) / a0);
    const float B2 = (float)((1.0 + alpha) / a0);
    const float A1 = (float)((-2.0 * cw) / a0);
    const float A2 = (float)((1.0 - alpha) / a0);

    const int blocks = BATCH * TPR;   /* 7552 */
    allpass_kernel<<<blocks, TPB, 0, stream>>>(x, y, B0, B1, B2, A1, A2);
}

// Round 9
// 205.085 us; speedup vs baseline: 1.0302x; 1.0302x over previous
//
#include <hip/hip_runtime.h>
#include <cmath>

#define T_LEN      480000
#define BATCH      64
#define WARM       16                    /* |pole|=0.414 -> 0.414^16 ~ 7.6e-7 */
#define TPB        256
#define WPB        (TPB / 64)            /* 4 waves per block */
#define WAVE_SAMP  256                   /* 64 lanes x 4 samples */
#define ROW_WAVES  (T_LEN / WAVE_SAMP)   /* 1875 exactly */
#define TOTAL_WAVES (BATCH * ROW_WAVES)  /* 120000 */
#define NBLOCKS    (TOTAL_WAVES / WPB)   /* 30000 */

/* native vector type: __builtin_nontemporal_* rejects HIP_vector_type */
typedef float f32x4 __attribute__((ext_vector_type(4)));

#define STEP(XN, YN)                                            \
    {                                                           \
        float u_ = fmaf(B0, (XN), fmaf(B1, x1, B2 * x2));       \
        (YN) = fmaf(-A1, y1, fmaf(-A2, y2, u_));                \
        x2 = x1; x1 = (XN); y2 = y1; y1 = (YN);                 \
    }

/* R9: transpose-free design.  All previous variants redistributed samples so
   a thread owns a contiguous run (LDS+barriers, or strided access) -- the one
   structural difference vs the 6.29 TB/s copy ubench (m13).  Here each lane
   owns 4 samples (lane-contiguous) and RE-LOADS its 16 warm-up samples via 5
   overlapping, individually fully-coalesced float4 loads.  The 5x transaction
   redundancy is same-line/same-wave and is absorbed by L1/L2 (loads must be
   CACHED for this); DRAM sees each line once.  No LDS, no barriers, no
   shuffles, no phases -- copy-structure + register recurrence. */

__global__ __launch_bounds__(TPB) void allpass_kernel(
    const float* __restrict__ x, float* __restrict__ y,
    float B0, float B1, float B2, float A1, float A2)
{
    const int lane = threadIdx.x & 63;
    const int gw   = blockIdx.x * WPB + (threadIdx.x >> 6);
    if (gw >= TOTAL_WAVES) return;        /* never trips: exact division */
    const int row  = gw / ROW_WAVES;
    const int wv   = gw % ROW_WAVES;      /* wave's position in its row */
    const int wb   = wv * WAVE_SAMP;
    const float* __restrict__ xr = x + (size_t)row * T_LEN;

    /* ---- 5 overlapping coalesced loads: samples [wb+4*lane-16, wb+4*lane+4) ---- */
    const int s0 = wb + 4 * lane - WARM;  /* 16B-aligned float offset */
    f32x4 W[5];
    if (__builtin_expect(wv != 0, 1)) {   /* wave-uniform branch */
        #pragma unroll
        for (int q = 0; q < 5; ++q)
            W[q] = *(const f32x4*)(xr + s0 + 4 * q);
    } else {                              /* row head: zeros before t=0 */
        #pragma unroll
        for (int q = 0; q < 5; ++q) {
            const int off = s0 + 4 * q;
            if (off < 0) W[q] = (f32x4){0.f, 0.f, 0.f, 0.f};
            else         W[q] = *(const f32x4*)(xr + off);
        }
    }

    /* ---- register recurrence: 16 warm-up + 4 real steps ---- */
    float x1 = 0.f, x2 = 0.f, y1 = 0.f, y2 = 0.f;
    #pragma unroll
    for (int q = 0; q < 4; ++q) {         /* warm-up, results discarded */
        float t;
        STEP(W[q].x, t); STEP(W[q].y, t); STEP(W[q].z, t); STEP(W[q].w, t);
    }
    f32x4 yv;
    STEP(W[4].x, yv.x); STEP(W[4].y, yv.y);
    STEP(W[4].z, yv.z); STEP(W[4].w, yv.w);

    /* lane-contiguous nt store: 64 lanes x 16B = 1KB full lines */
    __builtin_nontemporal_store(yv,
        (f32x4*)(y + (size_t)row * T_LEN + (size_t)(wb + 4 * lane)));
}

extern "C" void kernel_launch(void* const* d_in, const int* in_sizes, int n_in,
                              void* d_out, int out_size, void* d_ws, size_t ws_size,
                              hipStream_t stream) {
    const float* x = (const float*)d_in[0];
    float* y = (float*)d_out;

    const double sample_rate = 16000.0, central_freq = 4000.0, Q = 0.707;
    const double w0 = 2.0 * M_PI * central_freq / sample_rate;
    const double alpha = sin(w0) / (2.0 * Q);
    const double cw = cos(w0);
    const double a0 = 1.0 + alpha;
    const float B0 = (float)((1.0 - alpha) / a0);
    const float B1 = (float)((-2.0 * cw) / a0);
    const float B2 = (float)((1.0 + alpha) / a0);
    const float A1 = (float)((-2.0 * cw) / a0);
    const float A2 = (float)((1.0 - alpha) / a0);

    allpass_kernel<<<NBLOCKS, TPB, 0, stream>>>(x, y, B0, B1, B2, A1, A2);
}